// Round 4
// baseline (66.482 us; speedup 1.0000x reference)
//
#include <hip/hip_runtime.h>
#include <stdint.h>

#define D 128
#define NTHR 256
#define RPB 16   // rows per block: 4 waves x 4 rows

typedef float f2 __attribute__((ext_vector_type(2)));
typedef float f4 __attribute__((ext_vector_type(4)));
typedef _Float16 h16v __attribute__((ext_vector_type(16)));  // 32B: 8 {mu,ls} f16 pairs
typedef _Float16 h8v  __attribute__((ext_vector_type(8)));   // 16B: 8 f16

// ---- d_ws layout ----
#define WPK_OFF 0                       // uint32[i*D+j] = {f16 mu lo, f16 ls hi}, masked j<i
#define W1T_OFF (D * D * 4)             // 65536: f16[i*D+j] = W1[j][i], masked j>i
#define BIA_OFF (W1T_OFF + D * D * 2)   // 98304: f2[i] = {bmu[i], bls[i]}
#define WS_NEED (size_t)(BIA_OFF + D * 8)

#define DPP_ADD(v, ctrl)                                                          \
  (v) += __int_as_float(__builtin_amdgcn_update_dpp(0, __float_as_int(v), (ctrl), \
                                                    0xf, 0xf, true))
// all-lanes 16-lane butterfly: quad_perm xor1, xor2, row_ror:4, row_ror:8
#define RED16(v)       \
  do {                 \
    DPP_ADD(v, 0xB1);  \
    DPP_ADD(v, 0x4E);  \
    DPP_ADD(v, 0x124); \
    DPP_ADD(v, 0x128); \
  } while (0)

// ================= pre-pass: mask + transpose + f16-pack into d_ws =================
__global__ __launch_bounds__(256)
void iaf_prep(const float* __restrict__ W1, const float* __restrict__ Wmu,
              const float* __restrict__ Wls, const float* __restrict__ bmu,
              const float* __restrict__ bls, uint8_t* __restrict__ ws) {
  uint32_t* wpk = (uint32_t*)(ws + WPK_OFF);
  uint16_t* w1t = (uint16_t*)(ws + W1T_OFF);
  f2* biasp = (f2*)(ws + BIA_OFF);
  const int idx = blockIdx.x * 256 + threadIdx.x;
  if (idx < D * D) {
    const int i = idx >> 7, j = idx & (D - 1);
    const _Float16 pmu = (_Float16)((j < i) ? Wmu[idx] : 0.f);
    const _Float16 pls = (_Float16)((j < i) ? Wls[idx] : 0.f);
    wpk[idx] = (uint32_t)__builtin_bit_cast(uint16_t, pmu) |
               ((uint32_t)__builtin_bit_cast(uint16_t, pls) << 16);
    const _Float16 w1 = (_Float16)((j > i) ? W1[j * D + i] : 0.f);
    w1t[idx] = __builtin_bit_cast(uint16_t, w1);
    if (idx < D) {
      f2 b;
      b.x = bmu[idx];
      b.y = bls[idx];
      biasp[idx] = b;
    }
  }
}

// ================= main kernel: no LDS, f16 mix-fma, DPP reduce =================
// One step. WP/W1V are register sets (ping-pong, reloaded for step I+2 after use).
#define STEP(I, XE, ZRI, WP, W1V)                                                      \
  {                                                                                    \
    const f2 bb = biasp[(I)];                                                          \
    const float h0 = fmaxf(a0, 0.f), h1 = fmaxf(a1, 0.f);                              \
    const float h2 = fmaxf(a2, 0.f), h3 = fmaxf(a3, 0.f);                              \
    const float h4 = fmaxf(a4, 0.f), h5 = fmaxf(a5, 0.f);                              \
    const float h6 = fmaxf(a6, 0.f), h7 = fmaxf(a7, 0.f);                              \
    float mu0 = h0 * (float)WP[0], mu1 = h1 * (float)WP[2];                            \
    float ls0 = h0 * (float)WP[1], ls1 = h1 * (float)WP[3];                            \
    mu0 = fmaf(h2, (float)WP[4], mu0);  mu1 = fmaf(h3, (float)WP[6], mu1);             \
    ls0 = fmaf(h2, (float)WP[5], ls0);  ls1 = fmaf(h3, (float)WP[7], ls1);             \
    mu0 = fmaf(h4, (float)WP[8], mu0);  mu1 = fmaf(h5, (float)WP[10], mu1);            \
    ls0 = fmaf(h4, (float)WP[9], ls0);  ls1 = fmaf(h5, (float)WP[11], ls1);            \
    mu0 = fmaf(h6, (float)WP[12], mu0); mu1 = fmaf(h7, (float)WP[14], mu1);            \
    ls0 = fmaf(h6, (float)WP[13], ls0); ls1 = fmaf(h7, (float)WP[15], ls1);            \
    float mu_p = mu0 + mu1;                                                            \
    float ls_p = ls0 + ls1;                                                            \
    {                                                                                  \
      const int pf = ((I) + 2 < D) ? (I) + 2 : D - 1;                                  \
      WP = *(const h16v*)(wpk_b + pf * (D * 4));                                       \
    }                                                                                  \
    RED16(mu_p);                                                                       \
    RED16(ls_p);                                                                       \
    const float mu_t = mu_p + bb.x;                                                    \
    const float ls_t = ls_p + bb.y;                                                    \
    const float zi = fmaf((XE), __expf(ls_t), mu_t);                                   \
    ldj += ls_t;                                                                       \
    if (own) ZRI = zi;                                                                 \
    a0 = fmaf(zi, (float)W1V[0], a0); a1 = fmaf(zi, (float)W1V[1], a1);                \
    a2 = fmaf(zi, (float)W1V[2], a2); a3 = fmaf(zi, (float)W1V[3], a3);                \
    a4 = fmaf(zi, (float)W1V[4], a4); a5 = fmaf(zi, (float)W1V[5], a5);                \
    a6 = fmaf(zi, (float)W1V[6], a6); a7 = fmaf(zi, (float)W1V[7], a7);                \
    {                                                                                  \
      const int pf = ((I) + 2 < D) ? (I) + 2 : D - 1;                                  \
      W1V = *(const h8v*)(w1t_b + pf * (D * 2));                                       \
    }                                                                                  \
  }

__global__ __launch_bounds__(NTHR, 2)
void iaf_main(const float* __restrict__ x, const float* __restrict__ b1,
              const uint8_t* __restrict__ ws, float* __restrict__ out, int B) {
  const int tid = threadIdx.x;
  const int m = tid & 15;
  const int row = blockIdx.x * RPB + (tid >> 4);

  const float* __restrict__ xp = x + (size_t)row * D;
  const uint8_t* __restrict__ wpk_b = ws + WPK_OFF + m * 32;  // + i*512
  const uint8_t* __restrict__ w1t_b = ws + W1T_OFF + m * 16;  // + i*256
  const f2* __restrict__ biasp = (const f2*)(ws + BIA_OFF);

  float a0, a1, a2, a3, a4, a5, a6, a7;
  {
    const f4 t0 = *(const f4*)(b1 + m * 8);
    const f4 t1 = *(const f4*)(b1 + m * 8 + 4);
    a0 = t0.x; a1 = t0.y; a2 = t0.z; a3 = t0.w;
    a4 = t1.x; a5 = t1.y; a6 = t1.z; a7 = t1.w;
  }
  float zr[8];
  float ldj = 0.f;

  h16v wpA = *(const h16v*)(wpk_b);
  h8v  w1A = *(const h8v*)(w1t_b);
  h16v wpB = *(const h16v*)(wpk_b + D * 4);
  h8v  w1B = *(const h8v*)(w1t_b + D * 2);

  f4 x4a = *(const f4*)(xp);
  f4 x4b;

  for (int ob = 0; ob < 16; ++ob) {
    const int i0 = ob * 8;
    const bool own = (m == ob);
    x4b = *(const f4*)(xp + i0 + 4);
    STEP(i0 + 0, x4a.x, zr[0], wpA, w1A);
    STEP(i0 + 1, x4a.y, zr[1], wpB, w1B);
    STEP(i0 + 2, x4a.z, zr[2], wpA, w1A);
    STEP(i0 + 3, x4a.w, zr[3], wpB, w1B);
    x4a = *(const f4*)(xp + ((i0 + 8 < D) ? i0 + 8 : D - 4));
    STEP(i0 + 4, x4b.x, zr[4], wpA, w1A);
    STEP(i0 + 5, x4b.y, zr[5], wpB, w1B);
    STEP(i0 + 6, x4b.z, zr[6], wpA, w1A);
    STEP(i0 + 7, x4b.w, zr[7], wpB, w1B);
  }

  f4 o0, o1;
  o0.x = zr[0]; o0.y = zr[1]; o0.z = zr[2]; o0.w = zr[3];
  o1.x = zr[4]; o1.y = zr[5]; o1.z = zr[6]; o1.w = zr[7];
  float* zo = out + (size_t)row * D + m * 8;
  *(f4*)(zo) = o0;
  *(f4*)(zo + 4) = o1;
  if (m == 0) out[(size_t)B * D + row] = ldj;
}

// ================= fallback (R3 kernel, used only if ws_size < WS_NEED) =================
#define W1S 136
__device__ __forceinline__ uint16_t f2bf(float f) {
  uint32_t u = __float_as_uint(f);
  u += 0x7fffu + ((u >> 16) & 1u);
  return (uint16_t)(u >> 16);
}
__device__ __forceinline__ f2 unpk(uint32_t u) {
  f2 r;
  r.x = __uint_as_float(u << 16);
  r.y = __uint_as_float(u & 0xffff0000u);
  return r;
}
#define FSTEP(I, XE, ZRE, MKE, WM0, WM1, WL0, WL1)                  \
  {                                                                 \
    const float bmu_i = bmu[(I)];                                   \
    const float bls_i = bls[(I)];                                   \
    const f2 h0 = __builtin_elementwise_max(A0, (f2)0.f);           \
    const f2 h1 = __builtin_elementwise_max(A1, (f2)0.f);           \
    const f2 h2 = __builtin_elementwise_max(A2, (f2)0.f);           \
    const f2 h3 = __builtin_elementwise_max(A3, (f2)0.f);           \
    const f2 q0 = h0 * mk0, q1 = h1 * mk1;                          \
    const f2 q2 = h2 * mk2, q3 = h3 * mk3;                          \
    f2 am = q0 * WM0.xy;                                            \
    f2 al = q0 * WL0.xy;                                            \
    am = __builtin_elementwise_fma(q1, WM0.zw, am);                 \
    al = __builtin_elementwise_fma(q1, WL0.zw, al);                 \
    am = __builtin_elementwise_fma(q2, WM1.xy, am);                 \
    al = __builtin_elementwise_fma(q2, WL1.xy, al);                 \
    am = __builtin_elementwise_fma(q3, WM1.zw, am);                 \
    al = __builtin_elementwise_fma(q3, WL1.zw, al);                 \
    float mu_p = am.x + am.y;                                       \
    float ls_p = al.x + al.y;                                       \
    {                                                               \
      const int pfr = ((I) + 2 < D) ? (I) + 2 : D - 1;              \
      WM0 = *(const f4*)(wmup + pfr * D);                           \
      WM1 = *(const f4*)(wmup + pfr * D + 4);                       \
      WL0 = *(const f4*)(wlsp + pfr * D);                           \
      WL1 = *(const f4*)(wlsp + pfr * D + 4);                       \
    }                                                               \
    RED16(mu_p);                                                    \
    RED16(ls_p);                                                    \
    const float mu_t = mu_p + bmu_i;                                \
    const float ls_t = ls_p + bls_i;                                \
    const float zi = fmaf((XE), __expf(ls_t), mu_t);                \
    ldj += ls_t;                                                    \
    const uint4 wv = *(const uint4*)(w1p + (I)*W1S);                \
    if (own) {                                                      \
      ZRE = zi;                                                     \
      MKE = 1.f;                                                    \
    }                                                               \
    f2 zz;                                                          \
    zz.x = zi;                                                      \
    zz.y = zi;                                                      \
    A0 = __builtin_elementwise_fma(zz, unpk(wv.x), A0);             \
    A1 = __builtin_elementwise_fma(zz, unpk(wv.y), A1);             \
    A2 = __builtin_elementwise_fma(zz, unpk(wv.z), A2);             \
    A3 = __builtin_elementwise_fma(zz, unpk(wv.w), A3);             \
  }

__global__ __launch_bounds__(NTHR, 2)
void iaf_fb(const float* __restrict__ x, const float* __restrict__ W1,
            const float* __restrict__ b1, const float* __restrict__ Wmu,
            const float* __restrict__ bmu, const float* __restrict__ Wls,
            const float* __restrict__ bls, float* __restrict__ out, int B) {
  __shared__ uint16_t w1c[D * W1S];
  const int tid = threadIdx.x;
  for (int idx = tid; idx < D * D; idx += NTHR) {
    const int p = idx >> 7, q = idx & (D - 1);
    w1c[q * W1S + p] = f2bf((p > q) ? W1[idx] : 0.f);
  }
  __syncthreads();
  const int lane = tid & 63;
  const int m = lane & 15;
  const int row = blockIdx.x * RPB + (tid >> 4);
  const float* __restrict__ xp = x + (size_t)row * D;
  const float* __restrict__ wmup = Wmu + m * 8;
  const float* __restrict__ wlsp = Wls + m * 8;
  const uint16_t* __restrict__ w1p = w1c + m * 8;
  f2 A0, A1, A2, A3;
  {
    const f4 t0 = *(const f4*)(b1 + m * 8);
    const f4 t1 = *(const f4*)(b1 + m * 8 + 4);
    A0 = t0.xy; A1 = t0.zw; A2 = t1.xy; A3 = t1.zw;
  }
  f2 mk0 = (f2)0.f, mk1 = (f2)0.f, mk2 = (f2)0.f, mk3 = (f2)0.f;
  float zr0 = 0, zr1 = 0, zr2 = 0, zr3 = 0, zr4 = 0, zr5 = 0, zr6 = 0, zr7 = 0;
  float ldj = 0.f;
  f4 wmA0 = *(const f4*)(wmup);
  f4 wmA1 = *(const f4*)(wmup + 4);
  f4 wlA0 = *(const f4*)(wlsp);
  f4 wlA1 = *(const f4*)(wlsp + 4);
  f4 wmB0 = *(const f4*)(wmup + D);
  f4 wmB1 = *(const f4*)(wmup + D + 4);
  f4 wlB0 = *(const f4*)(wlsp + D);
  f4 wlB1 = *(const f4*)(wlsp + D + 4);
  f4 x4a = *(const f4*)(xp);
  f4 x4b;
  for (int ib = 0; ib < 16; ++ib) {
    const int i0 = ib * 8;
    const bool own = (m == ib);
    x4b = *(const f4*)(xp + i0 + 4);
    FSTEP(i0 + 0, x4a.x, zr0, mk0.x, wmA0, wmA1, wlA0, wlA1);
    FSTEP(i0 + 1, x4a.y, zr1, mk0.y, wmB0, wmB1, wlB0, wlB1);
    FSTEP(i0 + 2, x4a.z, zr2, mk1.x, wmA0, wmA1, wlA0, wlA1);
    FSTEP(i0 + 3, x4a.w, zr3, mk1.y, wmB0, wmB1, wlB0, wlB1);
    {
      const int nx = (i0 + 8 < D) ? i0 + 8 : D - 4;
      x4a = *(const f4*)(xp + nx);
    }
    FSTEP(i0 + 4, x4b.x, zr4, mk2.x, wmA0, wmA1, wlA0, wlA1);
    FSTEP(i0 + 5, x4b.y, zr5, mk2.y, wmB0, wmB1, wlB0, wlB1);
    FSTEP(i0 + 6, x4b.z, zr6, mk3.x, wmA0, wmA1, wlA0, wlA1);
    FSTEP(i0 + 7, x4b.w, zr7, mk3.y, wmB0, wmB1, wlB0, wlB1);
  }
  f4 o0, o1;
  o0.x = zr0; o0.y = zr1; o0.z = zr2; o0.w = zr3;
  o1.x = zr4; o1.y = zr5; o1.z = zr6; o1.w = zr7;
  float* zo = out + (size_t)row * D + m * 8;
  *(f4*)(zo) = o0;
  *(f4*)(zo + 4) = o1;
  if (m == 0) out[(size_t)B * D + row] = ldj;
}

extern "C" void kernel_launch(void* const* d_in, const int* in_sizes, int n_in,
                              void* d_out, int out_size, void* d_ws, size_t ws_size,
                              hipStream_t stream) {
  const float* x   = (const float*)d_in[0];
  const float* W1  = (const float*)d_in[1];
  const float* b1  = (const float*)d_in[2];
  const float* Wmu = (const float*)d_in[3];
  const float* bmu = (const float*)d_in[4];
  const float* Wls = (const float*)d_in[5];
  const float* bls = (const float*)d_in[6];
  float* out = (float*)d_out;

  const int B = in_sizes[0] / D;          // 8192
  const int grid = (B + RPB - 1) / RPB;   // 512

  if (ws_size >= WS_NEED) {
    iaf_prep<<<(D * D + 255) / 256, 256, 0, stream>>>(W1, Wmu, Wls, bmu, bls,
                                                      (uint8_t*)d_ws);
    iaf_main<<<grid, NTHR, 0, stream>>>(x, b1, (const uint8_t*)d_ws, out, B);
  } else {
    iaf_fb<<<grid, NTHR, 0, stream>>>(x, W1, b1, Wmu, bmu, Wls, bls, out, B);
  }
}